// Round 1
// baseline (526.580 us; speedup 1.0000x reference)
//
#include <hip/hip_runtime.h>

#define NEG (-1e30f)

constexpr int Tt = 384;   // timesteps
constexpr int Cc = 96;    // classes (blank = 95)
constexpr int Ll = 48;    // max label length
constexpr int PF = 4;     // prefetch depth (rows in flight)

__device__ __forceinline__ float lae3(float a, float b, float c) {
    float m = fmaxf(fmaxf(a, b), c);
    return m + __logf(__expf(a - m) + __expf(b - m) + __expf(c - m));
}
__device__ __forceinline__ float lae2(float a, float b) {
    float m = fmaxf(a, b);
    return m + __logf(__expf(a - m) + __expf(b - m));
}
__device__ __forceinline__ float wave_max(float v) {
#pragma unroll
    for (int off = 32; off > 0; off >>= 1) v = fmaxf(v, __shfl_xor(v, off, 64));
    return v;
}
__device__ __forceinline__ float wave_sum(float v) {
#pragma unroll
    for (int off = 32; off > 0; off >>= 1) v += __shfl_xor(v, off, 64);
    return v;
}
// select element e (0..95) of the row distributed as xlo(lanes 0..63)=c, xhi(lanes 0..31)=c+64
__device__ __forceinline__ float gather96(float xlo, float xhi, int e) {
    float g0 = __shfl(xlo, e & 63, 64);
    float g1 = __shfl(xhi, e & 63, 64);
    return (e < 64) ? g0 : g1;
}

__global__ __launch_bounds__(64) void zero_kernel(float* o) { *o = 0.0f; }

__global__ __launch_bounds__(64) void ctc_fwd(const int* __restrict__ labels,
                                              const float* __restrict__ pred,
                                              float* __restrict__ out,
                                              float invB) {
    const int b    = blockIdx.x;
    const int lane = threadIdx.x;
    const int blank = Cc - 1;
    const float* rowp = pred + (size_t)b * Tt * Cc;

    // ---- labels: lane i holds label i (i < Ll) ----
    int lab = 0, present = 0;
    if (lane < Ll) {
        int v = labels[(size_t)b * Ll + lane];
        present = (v != -1);
        lab = (v < 0) ? 0 : v;
    }
    unsigned long long pm = __ballot(present);
    int len = __popcll(pm);
    int vlim = 2 * len + 1;

    // ---- extended-label metadata per lane ----
    // lo states: s = lane (0..63);  hi states: s = 64+lane (only lane<=32 real)
    bool odd = (lane & 1);
    int jlo  = (lane - 1) >> 1;            // label index for odd lo state
    int jhi  = (lane + 63) >> 1;           // label index for odd hi state (s=64+lane)
    int jlo_c = jlo < 0 ? 0 : jlo;
    int jlo_p = (jlo - 1) < 0 ? 0 : (jlo - 1);
    int jhi_p = (jhi - 1) < 0 ? 0 : (jhi - 1);

    int lab_lo  = __shfl(lab, jlo_c, 64);
    int lab_lop = __shfl(lab, jlo_p, 64);
    int lab_hi  = __shfl(lab, jhi, 64);
    int lab_hip = __shfl(lab, jhi_p, 64);

    int  ext_lo = odd ? lab_lo : blank;
    int  ext_hi = odd ? lab_hi : blank;
    bool allow2_lo = odd && (lane >= 3) && (lab_lo != lab_lop);
    bool allow2_hi = odd && (lab_hi != lab_hip);          // s = 64+lane >= 65 >= 3 always
    bool valid_lo = (lane < vlim);
    bool valid_hi = (64 + lane < vlim);

    // ---- software-pipelined row loads ----
    float qlo[PF], qhi[PF];
#pragma unroll
    for (int i = 0; i < PF; ++i) {
        qlo[i] = rowp[i * Cc + lane];
        qhi[i] = (lane < 32) ? rowp[i * Cc + 64 + lane] : NEG;
    }

    float a_lo = NEG, a_hi = NEG;

    for (int t0 = 0; t0 < Tt; t0 += PF) {
#pragma unroll
        for (int j = 0; j < PF; ++j) {
            const int t = t0 + j;
            float xlo = qlo[j], xhi = qhi[j];
            const int tn = t + PF;
            if (tn < Tt) {
                qlo[j] = rowp[tn * Cc + lane];
                qhi[j] = (lane < 32) ? rowp[tn * Cc + 64 + lane] : NEG;
            }

            // log-softmax denominator for row t
            float m    = wave_max(fmaxf(xlo, xhi));
            float ssum = wave_sum(__expf(xlo - m) + __expf(xhi - m)); // exp(NEG-m)=0
            float logZ = m + __logf(ssum);

            float lp_lo = gather96(xlo, xhi, ext_lo) - logZ;
            float lp_hi = gather96(xlo, xhi, ext_hi) - logZ;

            if (t == 0) {
                a_lo = (lane == 0 || (lane == 1 && len > 0)) ? lp_lo : NEG;
                a_hi = NEG;
            } else {
                float u1 = __shfl_up(a_lo, 1, 64); u1 = (lane >= 1) ? u1 : NEG;
                float u2 = __shfl_up(a_lo, 2, 64); u2 = (lane >= 2 && allow2_lo) ? u2 : NEG;
                float b63 = __shfl(a_lo, 63, 64);
                float b62 = __shfl(a_lo, 62, 64);
                float h1 = __shfl_up(a_hi, 1, 64);
                float h2 = __shfl_up(a_hi, 2, 64);
                h1 = (lane == 0) ? b63 : h1;
                float h2x = (lane == 0) ? b62 : ((lane == 1) ? b63 : h2);
                h2x = allow2_hi ? h2x : NEG;

                float nlo = lae3(a_lo, u1, u2) + lp_lo;
                float nhi = lae3(a_hi, h1, h2x) + lp_hi;
                a_lo = valid_lo ? nlo : NEG;
                a_hi = valid_hi ? nhi : NEG;
            }
        }
    }

    // ---- finish: logaddexp(alpha[2*len], alpha[2*len-1]) ----
    int i1 = 2 * len;
    float v1 = gather96(a_lo, a_hi, i1);
    float v2 = (len > 0) ? gather96(a_lo, a_hi, i1 - 1) : NEG;
    float ll = lae2(v1, v2);
    if (lane == 0) atomicAdd(out, -ll * invB);
}

extern "C" void kernel_launch(void* const* d_in, const int* in_sizes, int n_in,
                              void* d_out, int out_size, void* d_ws, size_t ws_size,
                              hipStream_t stream) {
    const int*   labels = (const int*)d_in[0];
    const float* pred   = (const float*)d_in[1];
    float*       out    = (float*)d_out;

    const int B = in_sizes[0] / Ll;   // 1024

    hipLaunchKernelGGL(zero_kernel, dim3(1), dim3(64), 0, stream, out);
    hipLaunchKernelGGL(ctc_fwd, dim3(B), dim3(64), 0, stream,
                       labels, pred, out, 1.0f / (float)B);
}

// Round 2
// 253.282 us; speedup vs baseline: 2.0790x; 2.0790x over previous
//
#include <hip/hip_runtime.h>

#define NEG (-1e30f)

constexpr int Tt = 384;   // timesteps
constexpr int Cc = 96;    // classes (blank = 95)
constexpr int Ll = 48;    // max label length
constexpr int Gg = 8;     // rows per pipeline group
constexpr int NG = 24;    // groups per half (24*8 = 192)

__device__ __forceinline__ float lae2(float a, float b) {
    float m = fmaxf(a, b);
    return m + __logf(__expf(a - m) + __expf(b - m));
}
__device__ __forceinline__ float lae3(float a, float b, float c) {
    float m = fmaxf(fmaxf(a, b), c);
    return m + __logf(__expf(a - m) + __expf(b - m) + __expf(c - m));
}

// One half of the CTC lattice (192 timesteps), pair layout:
// lane i holds states 2i (even=blank) and 2i+1 (odd=label i).
// FWD: t = k ascending from 0.  BWD: t = 383-k descending.
template <bool FWD>
__device__ __forceinline__ void half_pass(const float2* __restrict__ rp2, int lane,
                                          int idx_h, int bitsel, bool allow2,
                                          bool valid_e, bool valid_o,
                                          float& st_e, float& st_o) {
    float2 q[Gg];
    float lpbC[Gg], lplC[Gg], lpbN[Gg], lplN[Gg];

    auto loadg = [&](int g) {
#pragma unroll
        for (int j = 0; j < Gg; ++j) {
            int k = g * Gg + j;
            int t = FWD ? k : (Tt - 1 - k);
            q[j] = (lane < 48) ? rp2[(size_t)t * 48 + lane] : make_float2(NEG, NEG);
        }
    };
    // compute log-softmax emissions (blank + per-lane label) for the group in q;
    // issues the loads for group `gnext` between the gathers and the butterflies.
    auto lp_from_q = [&](float* lpb, float* lpl, int gnext) {
        float s[Gg], gb[Gg], g0[Gg], g1[Gg];
#pragma unroll
        for (int j = 0; j < Gg; ++j)
            s[j] = (lane < 48) ? (__expf(q[j].x) + __expf(q[j].y)) : 0.0f;
#pragma unroll
        for (int j = 0; j < Gg; ++j) {
            gb[j] = __shfl(q[j].y, 47, 64);      // class 95 (blank)
            g0[j] = __shfl(q[j].x, idx_h, 64);   // class 2*idx_h
            g1[j] = __shfl(q[j].y, idx_h, 64);   // class 2*idx_h+1
        }
        if (gnext < NG) loadg(gnext);
#pragma unroll
        for (int off = 32; off >= 1; off >>= 1) {
#pragma unroll
            for (int j = 0; j < Gg; ++j) s[j] += __shfl_xor(s[j], off, 64);
        }
#pragma unroll
        for (int j = 0; j < Gg; ++j) {
            float lz = __logf(s[j]);
            lpb[j] = gb[j] - lz;
            lpl[j] = (bitsel ? g1[j] : g0[j]) - lz;
        }
    };

    loadg(0);
    lp_from_q(lpbC, lplC, 1);  // lp for group 0; loads group 1

    for (int g = 0; g < NG; ++g) {
        if (g + 1 < NG) lp_from_q(lpbN, lplN, g + 2);  // lp for g+1; loads g+2
#pragma unroll
        for (int j = 0; j < Gg; ++j) {
            if (FWD) {
                float ap = __shfl_up(st_o, 1, 64);
                ap = lane ? ap : NEG;                       // alpha(2i-1)
                float ne = lae2(st_e, ap) + lpbC[j];
                float no = lae3(st_o, st_e, allow2 ? ap : NEG) + lplC[j];
                st_e = valid_e ? ne : NEG;
                st_o = valid_o ? no : NEG;
            } else {
                float en = __shfl_down(st_e, 1, 64);        // beta(2i+2)
                float on = __shfl_down(st_o, 1, 64);        // beta(2i+3)
                float ne = lae2(st_e, st_o) + lpbC[j];
                float no = lae3(st_o, en, allow2 ? on : NEG) + lplC[j];
                st_e = valid_e ? ne : NEG;
                st_o = valid_o ? no : NEG;
            }
        }
        if (g + 1 < NG) {
#pragma unroll
            for (int j = 0; j < Gg; ++j) { lpbC[j] = lpbN[j]; lplC[j] = lplN[j]; }
        }
    }
}

__global__ __launch_bounds__(64) void zero_kernel(float* o) { *o = 0.0f; }

__global__ __launch_bounds__(128) void ctc_fb(const int* __restrict__ labels,
                                              const float* __restrict__ pred,
                                              float* __restrict__ out,
                                              float invB) {
    const int b    = blockIdx.x;
    const int lane = threadIdx.x & 63;
    const int wv   = threadIdx.x >> 6;
    const float2* rp2 = (const float2*)(pred + (size_t)b * Tt * Cc);

    // lane i holds label i
    int v = (lane < Ll) ? labels[(size_t)b * Ll + lane] : -1;
    int present = (lane < Ll) && (v != -1);
    int labv = (v < 0) ? 0 : v;
    unsigned long long pm = __ballot(present);
    int len = __popcll(pm);

    bool valid_e = (lane <= len);   // state 2*lane   < 2*len+1
    bool valid_o = (lane < len);    // state 2*lane+1 < 2*len+1
    int idx_h  = labv >> 1;
    int bitsel = labv & 1;
    int lab_p = __shfl_up(labv, 1, 64);
    int lab_n = __shfl_down(labv, 1, 64);

    __shared__ float sbe[64], sbo[64];

    float A_e = NEG, A_o = NEG;
    if (wv == 0) {
        // forward: t = 0..191
        bool allow2 = (lane >= 1) && (labv != lab_p);
        float a_e = (lane == 0) ? 0.0f : NEG;   // virtual pre-start state
        float a_o = NEG;
        half_pass<true>(rp2, lane, idx_h, bitsel, allow2, valid_e, valid_o, a_e, a_o);
        // transition half-step (no emission) to meet beta at t=192
        float ap = __shfl_up(a_o, 1, 64);
        ap = lane ? ap : NEG;
        A_e = lae2(a_e, ap);
        A_o = lae3(a_o, a_e, allow2 ? ap : NEG);
        A_e = valid_e ? A_e : NEG;
        A_o = valid_o ? A_o : NEG;
    } else {
        // backward: t = 383..192
        bool allow2 = (labv != lab_n);
        float b_e = (lane == len) ? 0.0f : NEG;  // virtual post-end state
        float b_o = NEG;
        half_pass<false>(rp2, lane, idx_h, bitsel, allow2, valid_e, valid_o, b_e, b_o);
        sbe[lane] = b_e;
        sbo[lane] = b_o;
    }
    __syncthreads();

    if (wv == 0) {
        float ve = A_e + sbe[lane];
        float vo = A_o + sbo[lane];
        float m = fmaxf(ve, vo);
#pragma unroll
        for (int off = 32; off >= 1; off >>= 1) m = fmaxf(m, __shfl_xor(m, off, 64));
        float ss = __expf(ve - m) + __expf(vo - m);
#pragma unroll
        for (int off = 32; off >= 1; off >>= 1) ss += __shfl_xor(ss, off, 64);
        float ll = m + __logf(ss);
        if (lane == 0) atomicAdd(out, -ll * invB);
    }
}

extern "C" void kernel_launch(void* const* d_in, const int* in_sizes, int n_in,
                              void* d_out, int out_size, void* d_ws, size_t ws_size,
                              hipStream_t stream) {
    const int*   labels = (const int*)d_in[0];
    const float* pred   = (const float*)d_in[1];
    float*       out    = (float*)d_out;

    const int B = in_sizes[0] / Ll;  // 1024

    hipLaunchKernelGGL(zero_kernel, dim3(1), dim3(64), 0, stream, out);
    hipLaunchKernelGGL(ctc_fb, dim3(B), dim3(128), 0, stream,
                       labels, pred, out, 1.0f / (float)B);
}

// Round 5
// 227.198 us; speedup vs baseline: 2.3177x; 1.1148x over previous
//
#include <hip/hip_runtime.h>

constexpr int Tt = 384;   // timesteps
constexpr int Cc = 96;    // classes (blank = 95)
constexpr int Ll = 48;    // max label length
constexpr int Gg = 8;     // rows per group (= rescale period)
constexpr int NG = 24;    // groups per half (24*8 = 192)

#define L2E 1.4426950408889634f
#define LN2 0.6931471805599453f
#define LNEG (-3.0e38f)

// ---- DPP helpers ----
template <int CTRL, int RM = 0xF>
__device__ __forceinline__ float dppf(float x) {
    return __int_as_float(
        __builtin_amdgcn_update_dpp(0, __float_as_int(x), CTRL, RM, 0xF, true));
}
template <int CTRL>
__device__ __forceinline__ int dppi(int x) {
    return __builtin_amdgcn_update_dpp(0, x, CTRL, 0xF, 0xF, true);
}
__device__ __forceinline__ float bcast63(float x) {
    return __int_as_float(__builtin_amdgcn_readlane(__float_as_int(x), 63));
}
// full-wave sum of non-negative values, result broadcast
__device__ __forceinline__ float wsum(float x) {
    x += dppf<0x111>(x);          // row_shr:1
    x += dppf<0x112>(x);          // row_shr:2
    x += dppf<0x114>(x);          // row_shr:4
    x += dppf<0x118>(x);          // row_shr:8
    x += dppf<0x142, 0xA>(x);     // row_bcast:15 -> rows 1,3
    x += dppf<0x143, 0xC>(x);     // row_bcast:31 -> rows 2,3
    return bcast63(x);
}
__device__ __forceinline__ float shup1(float x) { return dppf<0x138>(x); } // lane i <- i-1, 0 into lane 0
__device__ __forceinline__ float shdn1(float x) { return dppf<0x130>(x); } // lane i <- i+1, 0 into lane 63
__device__ __forceinline__ float exp2i(int d) {  // 2^d, d clamped to fp32-normal range
    d = d < -126 ? -126 : (d > 126 ? 126 : d);
    return __int_as_float((d + 127) << 23);
}

// One half of the CTC lattice (192 steps), linear probability space with a
// PER-LANE power-of-2 scale (value = st * 2^ls). Lane i holds states 2i,2i+1.
template <bool FWD>
__device__ __forceinline__ void half_pass(const float2* __restrict__ rp2, int lane,
                                          int idx_h, int bitsel, float allow2f,
                                          float& st_e, float& st_o, int& ls) {
    float2 q[Gg];
    float pbC[Gg], plC[Gg], pbN[Gg], plN[Gg];

    auto loadg = [&](int g) {
#pragma unroll
        for (int j = 0; j < Gg; ++j) {
            int k = g * Gg + j;
            int t = FWD ? k : (Tt - 1 - k);
            q[j] = (lane < 48) ? rp2[(size_t)t * 48 + lane] : make_float2(-1e4f, -1e4f);
        }
    };
    auto emit = [&](float* pb, float* pl, int gnext) {
        float ex[Gg], ey[Gg], s[Gg], gb[Gg], g0[Gg], g1[Gg];
#pragma unroll
        for (int j = 0; j < Gg; ++j) {
            ex[j] = exp2f(q[j].x * L2E);
            ey[j] = exp2f(q[j].y * L2E);
            s[j]  = ex[j] + ey[j];
        }
#pragma unroll
        for (int j = 0; j < Gg; ++j) {
            gb[j] = __shfl(ey[j], 47, 64);      // class 95 (blank)
            g0[j] = __shfl(ex[j], idx_h, 64);   // class 2*idx_h
            g1[j] = __shfl(ey[j], idx_h, 64);   // class 2*idx_h+1
        }
        if (gnext < NG) loadg(gnext);
#pragma unroll
        for (int j = 0; j < Gg; ++j) s[j] = wsum(s[j]);
#pragma unroll
        for (int j = 0; j < Gg; ++j) {
            float rZ = __builtin_amdgcn_rcpf(s[j]);
            pb[j] = gb[j] * rZ;
            pl[j] = (bitsel ? g1[j] : g0[j]) * rZ;
        }
    };

    float f   = 1.0f;            // 2^(ls_nbr - ls), constant within a group
    float a2f = allow2f;

    loadg(0);
    emit(pbC, plC, 1);

    for (int g = 0; g < NG; ++g) {
        if (g + 1 < NG) emit(pbN, plN, g + 2);
#pragma unroll
        for (int j = 0; j < Gg; ++j) {
            if (FWD) {
                float sh = shup1(st_o);                      // alpha(2i-1), lane i-1 scale
                float t0 = st_e + st_o;
                float ne = fmaf(f, sh, st_e) * pbC[j];
                float no = fmaf(a2f, sh, t0) * plC[j];
                st_e = ne; st_o = no;
            } else {
                float en = shdn1(st_e);                      // beta(2i+2)
                float on = shdn1(st_o);                      // beta(2i+3)
                float ne = (st_e + st_o) * pbC[j];
                float no = fmaf(a2f, on, fmaf(f, en, st_o)) * plC[j];
                st_e = ne; st_o = no;
            }
        }
        // ---- per-lane exact power-of-2 rescale ----
        float m = fmaxf(st_e, st_o);
        bool z = (m == 0.0f);
        int eb = (__float_as_int(m) >> 23) & 0xFF;
        eb = eb > 253 ? 253 : eb;
        float r = z ? 1.0f : __int_as_float((254 - eb) << 23);   // 2^(127-eb), exact
        st_e *= r; st_o *= r;
        ls += z ? 0 : (eb - 127);
        // ---- exponent adoption for zero lanes (front moves <= 8 lanes/group) ----
#pragma unroll
        for (int it = 0; it < 8; ++it) {
            int lsn = FWD ? dppi<0x138>(ls) : dppi<0x130>(ls);
            ls = z ? lsn : ls;
        }
        // ---- neighbor scale factor for next group ----
        int lsn2 = FWD ? dppi<0x138>(ls) : dppi<0x130>(ls);
        f = exp2i(lsn2 - ls);
        a2f = allow2f * f;
        if (g + 1 < NG) {
#pragma unroll
            for (int j = 0; j < Gg; ++j) { pbC[j] = pbN[j]; plC[j] = plN[j]; }
        }
    }
}

__global__ __launch_bounds__(64) void zero_kernel(float* o) { *o = 0.0f; }

__global__ __launch_bounds__(128) void ctc_fb(const int* __restrict__ labels,
                                              const float* __restrict__ pred,
                                              float* __restrict__ out,
                                              float invB) {
    const int b    = blockIdx.x;
    const int lane = threadIdx.x & 63;
    const int wv   = threadIdx.x >> 6;
    const float2* rp2 = (const float2*)(pred + (size_t)b * Tt * Cc);

    // lane i holds label i
    int v = (lane < Ll) ? labels[(size_t)b * Ll + lane] : -1;
    int present = (lane < Ll) && (v != -1);
    int labv = (v < 0) ? 0 : v;
    unsigned long long pm = __ballot(present);
    int len = __popcll(pm);

    int idx_h  = labv >> 1;
    int bitsel = labv & 1;
    int lab_p = __shfl(labv, (lane - 1) & 63, 64);
    int lab_n = __shfl(labv, (lane + 1) & 63, 64);

    __shared__ float sbe[64], sbo[64];
    __shared__ int   slsb[64];

    float Ae = 0.0f, Ao = 0.0f;
    int ls_f = 0;
    if (wv == 0) {
        // forward over t = 0..191, virtual pre-start state at lane 0
        float allow2f = (lane >= 1 && labv != lab_p) ? 1.0f : 0.0f;
        float a_e = (lane == 0) ? 1.0f : 0.0f;
        float a_o = 0.0f;
        half_pass<true>(rp2, lane, idx_h, bitsel, allow2f, a_e, a_o, ls_f);
        // transition half-step (no emission) to meet beta at t = 192
        float sh  = shup1(a_o);
        int   lsu = dppi<0x138>(ls_f);
        float fup = exp2i(lsu - ls_f);
        Ae = fmaf(fup, sh, a_e);
        Ao = fmaf(allow2f * fup, sh, a_e + a_o);
    } else {
        // backward over t = 383..192, virtual post-end state at lane == len
        float allow2f = (labv != lab_n) ? 1.0f : 0.0f;
        float b_e = (lane == len) ? 1.0f : 0.0f;
        float b_o = 0.0f;
        int ls_b = 0;
        half_pass<false>(rp2, lane, idx_h, bitsel, allow2f, b_e, b_o, ls_b);
        sbe[lane]  = b_e;
        sbo[lane]  = b_o;
        slsb[lane] = ls_b;
    }
    __syncthreads();

    if (wv == 0) {
        // combine in log2 domain with the integer exponents restored
        float be = sbe[lane], bo = sbo[lane];
        float base = (float)(ls_f + slsb[lane]);
        float l1 = (Ae > 0.0f && be > 0.0f) ? __log2f(Ae) + __log2f(be) + base : LNEG;
        float l2 = (Ao > 0.0f && bo > 0.0f) ? __log2f(Ao) + __log2f(bo) + base : LNEG;
        float mm = fmaxf(l1, l2);
#pragma unroll
        for (int off = 32; off >= 1; off >>= 1) mm = fmaxf(mm, __shfl_xor(mm, off, 64));
        float ss = exp2f(l1 - mm) + exp2f(l2 - mm);
#pragma unroll
        for (int off = 32; off >= 1; off >>= 1) ss += __shfl_xor(ss, off, 64);
        if (lane == 0) {
            float ll = (mm + __log2f(ss)) * LN2;
            atomicAdd(out, -ll * invB);
        }
    }
}

extern "C" void kernel_launch(void* const* d_in, const int* in_sizes, int n_in,
                              void* d_out, int out_size, void* d_ws, size_t ws_size,
                              hipStream_t stream) {
    const int*   labels = (const int*)d_in[0];
    const float* pred   = (const float*)d_in[1];
    float*       out    = (float*)d_out;

    const int B = in_sizes[0] / Ll;  // 1024

    hipLaunchKernelGGL(zero_kernel, dim3(1), dim3(64), 0, stream, out);
    hipLaunchKernelGGL(ctc_fb, dim3(B), dim3(128), 0, stream,
                       labels, pred, out, 1.0f / (float)B);
}